// Round 11
// baseline (218.559 us; speedup 1.0000x reference)
//
#include <hip/hip_runtime.h>
#include <hip/hip_bf16.h>

// MetaConv2d two-pass: hypernetwork materializes conv weights to workspace
// (kernel A), then a pure streaming conv consumes them (kernel B). Round 11.
// out[bn,t,o] = sum_{c,k} x[bn,t+k,c] * w[bn,o,c,k] + bias[bn,o]
//   w[bn,p]   = meta[bn,:]·w_lin_w[p,:] + w_lin_b[p],  p = o*192 + c*3 + k
//
// Rationale (r7/r9/r10 post-mortems): the fused kernel is gated by the
// per-phase hyper(L2 scattered loads)->barrier->conv chain; occupancy 88%
// (r10) still idles 70% of cycles. Two-pass removes w production from the
// consumer's critical path; every kernel-B load is a coalesced stream.
//
// W layout in ws: [node][o][j] bf16, j = k*64 + c, row padded to 200 shorts
// (100 dw, odd*4 -> 2-way banks on LDS B-reads). 25600 B/node, 210 MB total.
// ws too small -> chunked (2/4/8 node-chunks); still too small -> fused r6.

#define BN_TOT   8192
#define C_IN     64
#define C_OUT    64
#define M_DIM    32
#define S_OUT    62
#define WLW_ROWS 12288

#define OSTR2    200          // shorts per o-row in W (192 real + 8 pad)
#define NODE_W   12800        // 64*200 shorts per node in W
#define A_NPAD   1608         // kernel A LDS node stride (8*200 + 8)

typedef __attribute__((ext_vector_type(8))) short bf16x8;
typedef __attribute__((ext_vector_type(4))) float f32x4;

static __device__ __forceinline__ short f2bf(float f) {
    return __bfloat16_as_short(__float2bfloat16(f));
}

static __device__ __forceinline__ bf16x8 cvt8(float4 a, float4 b) {
    bf16x8 r;
    r[0] = f2bf(a.x); r[1] = f2bf(a.y); r[2] = f2bf(a.z); r[3] = f2bf(a.w);
    r[4] = f2bf(b.x); r[5] = f2bf(b.y); r[6] = f2bf(b.z); r[7] = f2bf(b.w);
    return r;
}

// ---------------- pre-pass 1: w_lin_w f32 -> bf16 ----------------
extern "C" __global__ void wlw_to_bf16(const float* __restrict__ src,
                                       short* __restrict__ dst) {
    const int i = (blockIdx.x * 256 + threadIdx.x) * 8;
    const float4 a = *reinterpret_cast<const float4*>(src + i);
    const float4 b = *reinterpret_cast<const float4*>(src + i + 4);
    *reinterpret_cast<bf16x8*>(dst + i) = cvt8(a, b);
}

// ---------------- pre-pass 2: wlb -> wlbR[o][k][c] f32 ----------------
extern "C" __global__ void wlb_rearr(const float* __restrict__ wlb,
                                     float* __restrict__ wlbR) {
    const int i = blockIdx.x * 256 + threadIdx.x;
    const int o = i / 192;
    const int r = i - o * 192;
    const int k = r >> 6;
    const int c = r & 63;
    wlbR[i] = wlb[o * 192 + c * 3 + k];
}

// ---------------- kernel A: w -> workspace ----------------
// Block: 16 nodes x 8 o-rows, 512 threads (8 waves; wave == o-row).
// 12 MFMA tiles/wave (4 ch x 3 k), D staged to LDS, coalesced dwordx4 out.
extern "C" __global__ void __launch_bounds__(512, 4)
hyper_write_w(const float* __restrict__ meta,    // [8192][32]
              const short* __restrict__ wlwbf,   // [12288][32] bf16
              const float* __restrict__ wlbR,    // [64][3][64] f32
              short* __restrict__ W,             // [nodes][64][200] bf16
              int bn_base)
{
    __shared__ short st[16 * A_NPAD];            // [node][8 o][200] (+8 pad/node)

    const int tid  = threadIdx.x;
    const int wave = tid >> 6;                   // 0..7 == o-row within block
    const int lane = tid & 63;
    const int l16  = lane & 15;
    const int g    = lane >> 4;
    const int bn0  = bn_base + blockIdx.x * 16;
    const int og0  = blockIdx.y * 8;
    const int og   = og0 + wave;

    // meta B-fragment: 16 node columns, all used
    bf16x8 metaF;
    {
        const float* mp = meta + (size_t)(bn0 + l16) * M_DIM + g * 8;
        metaF = cvt8(*reinterpret_cast<const float4*>(mp),
                     *reinterpret_cast<const float4*>(mp + 4));
    }

    // 12 tiles = 2 groups of 6 (proven flight depth)
    #pragma unroll 1
    for (int cp = 0; cp < 2; ++cp) {
        #pragma unroll
        for (int ci = 0; ci < 2; ++ci) {
            const int ch4 = cp * 2 + ci;         // c-16-group 0..3
            #pragma unroll
            for (int k = 0; k < 3; ++k) {
                const int c  = ch4 * 16 + l16;   // A-row = c
                const int pr = og * 192 + c * 3 + k;
                const bf16x8 aF = *reinterpret_cast<const bf16x8*>(
                    wlwbf + (size_t)pr * M_DIM + g * 8);
                const float4 cf = *reinterpret_cast<const float4*>(
                    wlbR + (og * 3 + k) * 64 + ch4 * 16 + g * 4);
                f32x4 Cf; Cf[0] = cf.x; Cf[1] = cf.y; Cf[2] = cf.z; Cf[3] = cf.w;
                const f32x4 d = __builtin_amdgcn_mfma_f32_16x16x32_bf16(aF, metaF, Cf, 0, 0, 0);
                // lane holds node=l16, c-rows ch4*16 + g*4 + r
                const int off = l16 * A_NPAD + wave * OSTR2 + k * 64 + ch4 * 16 + g * 4;
                *reinterpret_cast<short4*>(&st[off]) =
                    make_short4(f2bf(d[0]), f2bf(d[1]), f2bf(d[2]), f2bf(d[3]));
            }
        }
    }
    __syncthreads();

    // coalesced write: 16 nodes x 1600 shorts = 3200 dwordx4 units
    const size_t wb = (size_t)(blockIdx.x * 16) * NODE_W + (size_t)og0 * OSTR2;
    #pragma unroll
    for (int i = 0; i < 7; ++i) {
        const int u = i * 512 + tid;
        if (u < 3200) {
            const int nd = u / 200;              // 200 x4-units per node slice
            const int rc = u - nd * 200;
            const int4 v = *reinterpret_cast<const int4*>(&st[nd * A_NPAD + rc * 8]);
            *reinterpret_cast<int4*>(W + wb + (size_t)nd * NODE_W + rc * 8) = v;
        }
    }
}

// ---------------- kernel B: streaming conv ----------------
// Block: 8 nodes, 1024 threads (16 waves = node x t-half), grid nodes/8.
// x staged once (r6 swizzled xsh); w staged per o-quarter with T14 reg
// prefetch: load(q+1) issued before conv(q), ds_write after the barrier.
#define B_DYN  ((32768 + 25600) * 2)             // 116736 B dynamic LDS

extern "C" __global__ void __launch_bounds__(1024, 4)
conv_stream(const float* __restrict__ meta,      // [8192][32]
            const float* __restrict__ x,         // [8192][64][64]
            const short* __restrict__ W,         // [nodes][64][200] bf16 (ws)
            const float* __restrict__ blw,       // [64][32]
            const float* __restrict__ blb,       // [64]
            float* __restrict__ out,             // [8192][62][64]
            int bn_base)
{
    extern __shared__ __align__(16) short dynsm[];
    short* xsh = dynsm;                          // [8][64][64] swizzled
    short* wsh = dynsm + 32768;                  // [8][16 o][200]
    __shared__ float bias_s[8][C_OUT];

    const int tid   = threadIdx.x;
    const int wave  = tid >> 6;
    const int lane  = tid & 63;
    const int l16   = lane & 15;
    const int g     = lane >> 4;
    const int node  = wave & 7;
    const int thalf = wave >> 3;
    const int ln0   = blockIdx.x * 8;            // local node base (W index)
    const int bn0   = bn_base + ln0;             // global node base

    // ---- w quarter staging: regs <-> LDS (T14 split) ----
    int4 wr[2][4];                               // static idx only (rule #20)
    auto load_w = [&](int q, int s) {
        #pragma unroll
        for (int i = 0; i < 4; ++i) {
            const int u = i * 1024 + tid;        // x4-unit id, 3200 per quarter
            if (u < 3200) {
                const int nd = u / 400;          // 400 x4-units per node-quarter
                const int rc = u - nd * 400;
                wr[s][i] = *reinterpret_cast<const int4*>(
                    W + (size_t)(ln0 + nd) * NODE_W + q * 3200 + rc * 8);
            }
        }
    };
    auto write_w = [&](int s) {
        #pragma unroll
        for (int i = 0; i < 4; ++i) {
            const int u = i * 1024 + tid;
            if (u < 3200) {
                const int nd = u / 400;
                const int rc = u - nd * 400;
                *reinterpret_cast<int4*>(wsh + nd * 3200 + rc * 8) = wr[s][i];
            }
        }
    };

    load_w(0, 0);                                // oldest in HBM queue

    // ---- stage x slab (r6 proven: swizzled, deep queue) ----
    {
        const float* xsrc = x + (size_t)(bn0 + node) * (64 * C_IN);
        short* xd = xsh + node * 4096;
        const int ts0 = thalf * 32;
        #pragma unroll
        for (int i = 0; i < 4; ++i) {
            const int gi = i * 64 + lane;
            const int tl = ts0 + (gi >> 3);
            const int gr = gi & 7;
            const float4 a = *reinterpret_cast<const float4*>(xsrc + tl * 64 + gr * 8);
            const float4 b = *reinterpret_cast<const float4*>(xsrc + tl * 64 + gr * 8 + 4);
            const int so = (gr * 8) ^ ((tl & 7) << 3);
            *reinterpret_cast<bf16x8*>(xd + tl * 64 + so) = cvt8(a, b);
        }
    }

    // per-block bias table (tid < 512)
    if (tid < 8 * C_OUT) {
        const int bnode = tid >> 6;
        const int o     = tid & 63;
        const float* mrow = meta + (size_t)(bn0 + bnode) * M_DIM;
        const float* brow = blw + o * M_DIM;
        float s = blb[o];
        #pragma unroll
        for (int m = 0; m < M_DIM; ++m) s += mrow[m] * brow[m];
        bias_s[bnode][o] = s;
    }

    const f32x4 ZV = {0.f, 0.f, 0.f, 0.f};
    f32x4 acc[2][4];                             // [t-tile][o-quarter], static idx
    #pragma unroll
    for (int t = 0; t < 2; ++t)
        #pragma unroll
        for (int o = 0; o < 4; ++o) acc[t][o] = ZV;

    write_w(0);                                  // waits w0 loads (vmcnt)
    __syncthreads();                             // x + w0 visible

    #pragma unroll
    for (int q = 0; q < 4; ++q) {
        if (q < 3) load_w(q + 1, (q + 1) & 1);   // fly during conv(q)

        // ---- conv(q): o-tile = q*16 + l16 ----
        const short* wn = wsh + node * 3200;
        const short* xn = xsh + node * 4096;
        bf16x8 B[2][3];
        #pragma unroll
        for (int cc2 = 0; cc2 < 2; ++cc2)
            #pragma unroll
            for (int k = 0; k < 3; ++k)
                B[cc2][k] = *reinterpret_cast<const bf16x8*>(
                    wn + l16 * OSTR2 + k * 64 + cc2 * 32 + g * 8);
        #pragma unroll
        for (int ttl = 0; ttl < 2; ++ttl) {
            #pragma unroll
            for (int cc2 = 0; cc2 < 2; ++cc2) {
                #pragma unroll
                for (int k = 0; k < 3; ++k) {
                    int row = thalf * 32 + ttl * 16 + l16 + k;
                    row = row < 63 ? row : 63;   // t>=62 rows discarded
                    const int so = (cc2 * 32 + g * 8) ^ ((row & 7) << 3);
                    const bf16x8 A = *reinterpret_cast<const bf16x8*>(
                        xn + row * 64 + so);
                    acc[ttl][q] = __builtin_amdgcn_mfma_f32_16x16x32_bf16(
                        A, B[cc2][k], acc[ttl][q], 0, 0, 0);
                }
            }
        }
        __syncthreads();                         // all reads of wsh(q) done
        if (q < 3) {
            write_w((q + 1) & 1);
            __syncthreads();                     // w(q+1) visible
        }
    }

    // ---- epilogue: add bias, store f32 ----
    float* ob = out + (size_t)(bn0 + node) * (S_OUT * C_OUT);
    #pragma unroll
    for (int ttl = 0; ttl < 2; ++ttl) {
        #pragma unroll
        for (int ot = 0; ot < 4; ++ot) {
            const int o  = ot * 16 + l16;
            const float bv = bias_s[node][o];
            #pragma unroll
            for (int r = 0; r < 4; ++r) {
                const int t = thalf * 32 + ttl * 16 + g * 4 + r;
                if (t < S_OUT) ob[t * C_OUT + o] = acc[ttl][ot][r] + bv;
            }
        }
    }
}

// ---------------- fallback: fused r6 kernel (no workspace) ----------------
#define OSTRF    104
#define WNODEF   (16 * OSTRF + 8)
#define WBUFF    (8 * WNODEF)

extern "C" __global__ void __launch_bounds__(1024, 4)
metaconv_fused_nows(const float* __restrict__ meta, const float* __restrict__ x,
                    const float* __restrict__ wlw, const float* __restrict__ wlb,
                    const float* __restrict__ blw, const float* __restrict__ blb,
                    float* __restrict__ out)
{
    __shared__ short wsh[2 * WBUFF];
    __shared__ short xshf[8 * 4096];
    __shared__ float bias_s[8][C_OUT];

    const int tid = threadIdx.x, wave = tid >> 6, lane = tid & 63;
    const int l16 = lane & 15, g = lane >> 4;
    const int node = wave & 7, thalf = wave >> 3;
    const int bn0 = blockIdx.x * 8;

    {
        const float* xsrc = x + (size_t)(bn0 + node) * (64 * C_IN);
        short* xd = xshf + node * 4096;
        const int ts0 = thalf * 32;
        #pragma unroll
        for (int i = 0; i < 4; ++i) {
            const int gi = i * 64 + lane;
            const int tl = ts0 + (gi >> 3), gr = gi & 7;
            const float4 a = *reinterpret_cast<const float4*>(xsrc + tl * 64 + gr * 8);
            const float4 b = *reinterpret_cast<const float4*>(xsrc + tl * 64 + gr * 8 + 4);
            const int so = (gr * 8) ^ ((tl & 7) << 3);
            *reinterpret_cast<bf16x8*>(xd + tl * 64 + so) = cvt8(a, b);
        }
    }
    if (tid < 8 * C_OUT) {
        const int bnode = tid >> 6, o = tid & 63;
        const float* mrow = meta + (size_t)(bn0 + bnode) * M_DIM;
        const float* brow = blw + o * M_DIM;
        float s = blb[o];
        #pragma unroll
        for (int m = 0; m < M_DIM; ++m) s += mrow[m] * brow[m];
        bias_s[bnode][o] = s;
    }
    bf16x8 metaF;
    {
        const float* mp = meta + (size_t)(bn0 + (l16 & 7)) * M_DIM + g * 8;
        metaF = cvt8(*reinterpret_cast<const float4*>(mp),
                     *reinterpret_cast<const float4*>(mp + 4));
    }
    auto hyper = [&](int c0, int oq, int buf) {
        const int og = oq * 16 + wave;
        short* wd = wsh + buf * WBUFF;
        #pragma unroll
        for (int ch = 0; ch < 2; ++ch) {
            #pragma unroll
            for (int k = 0; k < 3; ++k) {
                const int pr = og * 192 + (c0 + ch * 16 + l16) * 3 + k;
                const float* wp = wlw + (size_t)pr * M_DIM + g * 8;
                const bf16x8 aF = cvt8(*reinterpret_cast<const float4*>(wp),
                                       *reinterpret_cast<const float4*>(wp + 4));
                const int cb = c0 + ch * 16 + g * 4, pb = og * 192 + k;
                f32x4 Cf;
                Cf[0] = wlb[pb + (cb + 0) * 3]; Cf[1] = wlb[pb + (cb + 1) * 3];
                Cf[2] = wlb[pb + (cb + 2) * 3]; Cf[3] = wlb[pb + (cb + 3) * 3];
                const f32x4 d = __builtin_amdgcn_mfma_f32_16x16x32_bf16(aF, metaF, Cf, 0, 0, 0);
                if (l16 < 8) {
                    const int off = l16 * WNODEF + wave * OSTRF + k * 32 + ch * 16 + g * 4;
                    *reinterpret_cast<short4*>(&wd[off]) =
                        make_short4(f2bf(d[0]), f2bf(d[1]), f2bf(d[2]), f2bf(d[3]));
                }
            }
        }
    };
    const f32x4 ZV = {0.f, 0.f, 0.f, 0.f};
    f32x4 acc[2][4];
    #pragma unroll
    for (int t = 0; t < 2; ++t)
        #pragma unroll
        for (int o = 0; o < 4; ++o) acc[t][o] = ZV;

    hyper(0, 0, 0);
    __syncthreads();
    #pragma unroll
    for (int cc = 0; cc < 2; ++cc) {
        #pragma unroll
        for (int oq = 0; oq < 4; ++oq) {
            const int P = cc * 4 + oq;
            if (P < 7) hyper(((P + 1) >> 2) * 32, (P + 1) & 3, (P + 1) & 1);
            const short* wn = wsh + (P & 1) * WBUFF + node * WNODEF;
            const short* xn = xshf + node * 4096;
            bf16x8 B[3];
            #pragma unroll
            for (int k = 0; k < 3; ++k)
                B[k] = *reinterpret_cast<const bf16x8*>(wn + l16 * OSTRF + k * 32 + g * 8);
            #pragma unroll
            for (int ttl = 0; ttl < 2; ++ttl)
                #pragma unroll
                for (int k = 0; k < 3; ++k) {
                    int row = thalf * 32 + ttl * 16 + l16 + k;
                    row = row < 63 ? row : 63;
                    const int so = (cc * 32 + g * 8) ^ ((row & 7) << 3);
                    const bf16x8 A = *reinterpret_cast<const bf16x8*>(xn + row * 64 + so);
                    acc[ttl][oq] = __builtin_amdgcn_mfma_f32_16x16x32_bf16(
                        A, B[k], acc[ttl][oq], 0, 0, 0);
                }
            __syncthreads();
        }
    }
    float* ob = out + (size_t)(bn0 + node) * (S_OUT * C_OUT);
    #pragma unroll
    for (int ttl = 0; ttl < 2; ++ttl)
        #pragma unroll
        for (int ot = 0; ot < 4; ++ot) {
            const int o = ot * 16 + l16;
            const float bv = bias_s[node][o];
            #pragma unroll
            for (int r = 0; r < 4; ++r) {
                const int t = thalf * 32 + ttl * 16 + g * 4 + r;
                if (t < S_OUT) ob[t * C_OUT + o] = acc[ttl][ot][r] + bv;
            }
        }
}

// ---------------- launcher ----------------
extern "C" void kernel_launch(void* const* d_in, const int* in_sizes, int n_in,
                              void* d_out, int out_size, void* d_ws, size_t ws_size,
                              hipStream_t stream) {
    const float* meta = (const float*)d_in[0];
    const float* x    = (const float*)d_in[1];
    const float* wlw  = (const float*)d_in[2];
    const float* wlb  = (const float*)d_in[3];
    const float* blw  = (const float*)d_in[4];
    const float* blb  = (const float*)d_in[5];
    float* out = (float*)d_out;
    (void)in_sizes; (void)n_in; (void)out_size;

    const size_t fixed = (size_t)WLW_ROWS * M_DIM * 2 + (size_t)WLW_ROWS * 4; // 835584
    int nchunk = 0;
    for (int n = 1; n <= 8; n *= 2) {
        if (ws_size >= fixed + (size_t)(BN_TOT / n) * NODE_W * 2) { nchunk = n; break; }
    }

    if (nchunk) {
        short* wlwbf = (short*)d_ws;
        float* wlbR  = (float*)((char*)d_ws + (size_t)WLW_ROWS * M_DIM * 2);
        short* Warea = (short*)((char*)d_ws + fixed);
        (void)hipFuncSetAttribute((const void*)&conv_stream,
                                  hipFuncAttributeMaxDynamicSharedMemorySize, B_DYN);
        wlw_to_bf16<<<dim3(WLW_ROWS * M_DIM / (256 * 8)), dim3(256), 0, stream>>>(wlw, wlwbf);
        wlb_rearr<<<dim3(WLW_ROWS / 256), dim3(256), 0, stream>>>(wlb, wlbR);
        const int nodes = BN_TOT / nchunk;
        for (int c = 0; c < nchunk; ++c) {
            hyper_write_w<<<dim3(nodes / 16, 8), dim3(512), 0, stream>>>(
                meta, wlwbf, wlbR, Warea, c * nodes);
            conv_stream<<<dim3(nodes / 8), dim3(1024), B_DYN, stream>>>(
                meta, x, Warea, blw, blb, out, c * nodes);
        }
    } else {
        metaconv_fused_nows<<<dim3(BN_TOT / 8), dim3(1024), 0, stream>>>(
            meta, x, wlw, wlb, blw, blb, out);
    }
}

// Round 12
// 192.766 us; speedup vs baseline: 1.1338x; 1.1338x over previous
//
#include <hip/hip_runtime.h>
#include <hip/hip_bf16.h>

// MetaConv2d two-pass, round 12.
// Kernel A: hypernetwork materializes conv weights W2 into workspace in the
// EXACT B-fragment consumption order of kernel B:
//   W2[node][q][cc2][k][l16][g] bf16, 16B units  (12288 shorts / node)
//   (o = q*16 + l16, c = cc2*32 + g*8 + e, per-node 24.6 KB)
// Kernel B: pure streaming conv. x staged once in LDS (r6 swizzle); W
// B-fragments loaded global->reg as contiguous 1KB wave-loads; NO barriers in
// the main loop (waves independent); output stored per o-tile (acc = 8 regs).
//
// r11 post-mortem: reg<->LDS W staging spilled (WRITE 331MB) but streamed at
// 3.7 TB/s -> keep the two-pass shape, delete the staging machinery.

#define BN_TOT   8192
#define C_IN     64
#define C_OUT    64
#define M_DIM    32
#define S_OUT    62
#define WLW_ROWS 12288

#define NODE_W2  12288        // shorts per node in W2 (4q*3072)
#define A_STN    1544         // kernel A LDS node stride (8*192 + 8)

typedef __attribute__((ext_vector_type(8))) short bf16x8;
typedef __attribute__((ext_vector_type(4))) float f32x4;

static __device__ __forceinline__ short f2bf(float f) {
    return __bfloat16_as_short(__float2bfloat16(f));
}

static __device__ __forceinline__ bf16x8 cvt8(float4 a, float4 b) {
    bf16x8 r;
    r[0] = f2bf(a.x); r[1] = f2bf(a.y); r[2] = f2bf(a.z); r[3] = f2bf(a.w);
    r[4] = f2bf(b.x); r[5] = f2bf(b.y); r[6] = f2bf(b.z); r[7] = f2bf(b.w);
    return r;
}

// ---- pre-pass 1: w_lin_w f32 -> bf16, permuted to kernel A's load order ----
// WP[o][ch4][k][c16][m] : each A-tile load = contiguous 2KB per wave.
extern "C" __global__ void wlw_perm_bf16(const float* __restrict__ src,
                                         short* __restrict__ dst) {
    const int i = blockIdx.x * 256 + threadIdx.x;   // 49152 = 12288 rows x 4
    const int p = i >> 2;
    const int g = i & 3;
    const int o = p / 192;
    const int r = p - o * 192;
    const int c = r / 3;
    const int k = r - c * 3;
    const float4 a = *reinterpret_cast<const float4*>(src + p * 32 + g * 8);
    const float4 b = *reinterpret_cast<const float4*>(src + p * 32 + g * 8 + 4);
    const int off = o * 6144 + (c >> 4) * 1536 + k * 512 + (c & 15) * 32 + g * 8;
    *reinterpret_cast<bf16x8*>(dst + off) = cvt8(a, b);
}

// ---- pre-pass 2: wlb -> wlbR[o][k][c] f32 ----
extern "C" __global__ void wlb_rearr(const float* __restrict__ wlb,
                                     float* __restrict__ wlbR) {
    const int i = blockIdx.x * 256 + threadIdx.x;
    const int o = i / 192;
    const int r = i - o * 192;
    const int k = r >> 6;
    const int c = r & 63;
    wlbR[i] = wlb[o * 192 + c * 3 + k];
}

// ---------------- kernel A: hypernetwork -> W2 ----------------
// Block: 16 nodes x 8 o-rows (512 thr, wave == o-row). 12 MFMA tiles/wave.
extern "C" __global__ void __launch_bounds__(512, 4)
hyper_write_w(const float* __restrict__ meta,    // [8192][32]
              const short* __restrict__ WP,      // permuted wlw bf16
              const float* __restrict__ wlbR,    // [64][3][64] f32
              short* __restrict__ W2,            // [nodes][12288] bf16
              int bn_base)
{
    __shared__ short st[16 * A_STN];             // [node][8 ow][192] (+8 pad)

    const int tid  = threadIdx.x;
    const int wave = tid >> 6;                   // ow 0..7
    const int lane = tid & 63;
    const int l16  = lane & 15;
    const int g    = lane >> 4;
    const int bn0  = bn_base + blockIdx.x * 16;
    const int og   = blockIdx.y * 8 + wave;

    bf16x8 metaF;                                // B-frag: 16 node columns
    {
        const float* mp = meta + (size_t)(bn0 + l16) * M_DIM + g * 8;
        metaF = cvt8(*reinterpret_cast<const float4*>(mp),
                     *reinterpret_cast<const float4*>(mp + 4));
    }

    #pragma unroll 1
    for (int cp = 0; cp < 2; ++cp) {
        #pragma unroll
        for (int ci = 0; ci < 2; ++ci) {
            const int ch4 = cp * 2 + ci;         // c-16-group 0..3
            #pragma unroll
            for (int k = 0; k < 3; ++k) {
                const bf16x8 aF = *reinterpret_cast<const bf16x8*>(
                    WP + og * 6144 + ch4 * 1536 + k * 512 + l16 * 32 + g * 8);
                const float4 cf = *reinterpret_cast<const float4*>(
                    wlbR + (og * 3 + k) * 64 + ch4 * 16 + g * 4);
                f32x4 Cf; Cf[0] = cf.x; Cf[1] = cf.y; Cf[2] = cf.z; Cf[3] = cf.w;
                const f32x4 d = __builtin_amdgcn_mfma_f32_16x16x32_bf16(aF, metaF, Cf, 0, 0, 0);
                // lane holds node=l16, c = ch4*16 + g*4 + r
                *reinterpret_cast<short4*>(
                    &st[l16 * A_STN + wave * 192 + k * 64 + ch4 * 16 + g * 4]) =
                    make_short4(f2bf(d[0]), f2bf(d[1]), f2bf(d[2]), f2bf(d[3]));
            }
        }
    }
    __syncthreads();

    // write-out in W2 order: 3072 16B-units = 16 nodes x 8 ow x 3 k x 8 gb
    const int nb = blockIdx.x * 16;
    #pragma unroll
    for (int i = 0; i < 6; ++i) {
        const int u    = i * 512 + tid;
        const int node = u / 192;
        const int rem  = u - node * 192;
        const int ow   = rem / 24;
        const int rk   = rem - ow * 24;
        const int k    = rk >> 3;
        const int gb   = rk & 7;
        const int4 v = *reinterpret_cast<const int4*>(
            &st[node * A_STN + ow * 192 + k * 64 + gb * 8]);
        const int og2 = blockIdx.y * 8 + ow;
        *reinterpret_cast<int4*>(
            W2 + (size_t)(nb + node) * NODE_W2 + (og2 >> 4) * 3072 +
            (gb >> 2) * 1536 + k * 512 + (og2 & 15) * 32 + (gb & 3) * 8) = v;
    }
}

// ---------------- kernel B: barrier-free streaming conv ----------------
// Block: 8 nodes, 1024 thr (16 waves = node x t-half), LDS = x 64KB + bias.
extern "C" __global__ void __launch_bounds__(1024, 4)
conv_stream(const float* __restrict__ meta,      // [8192][32]
            const float* __restrict__ x,         // [8192][64][64]
            const short* __restrict__ W2,        // [nodes][12288] bf16 (ws)
            const float* __restrict__ blw,       // [64][32]
            const float* __restrict__ blb,       // [64]
            float* __restrict__ out,             // [8192][62][64]
            int bn_base)
{
    __shared__ short xsh[8 * 4096];              // x bf16, row-swizzled
    __shared__ float bias_s[8][C_OUT];

    const int tid   = threadIdx.x;
    const int wave  = tid >> 6;
    const int lane  = tid & 63;
    const int l16   = lane & 15;
    const int g     = lane >> 4;
    const int node  = wave & 7;
    const int thalf = wave >> 3;
    const int ln0   = blockIdx.x * 8;
    const int bn0   = bn_base + ln0;

    // ---- stage x slab (r6 proven: swizzled, deep queue) ----
    {
        const float* xsrc = x + (size_t)(bn0 + node) * (64 * C_IN);
        short* xd = xsh + node * 4096;
        const int ts0 = thalf * 32;
        #pragma unroll
        for (int i = 0; i < 4; ++i) {
            const int gi = i * 64 + lane;
            const int tl = ts0 + (gi >> 3);
            const int gr = gi & 7;
            const float4 a = *reinterpret_cast<const float4*>(xsrc + tl * 64 + gr * 8);
            const float4 b = *reinterpret_cast<const float4*>(xsrc + tl * 64 + gr * 8 + 4);
            const int so = (gr * 8) ^ ((tl & 7) << 3);
            *reinterpret_cast<bf16x8*>(xd + tl * 64 + so) = cvt8(a, b);
        }
    }

    if (tid < 8 * C_OUT) {                       // bias table
        const int bnode = tid >> 6;
        const int o     = tid & 63;
        const float* mrow = meta + (size_t)(bn0 + bnode) * M_DIM;
        const float* brow = blw + o * M_DIM;
        float s = blb[o];
        #pragma unroll
        for (int m = 0; m < M_DIM; ++m) s += mrow[m] * brow[m];
        bias_s[bnode][o] = s;
    }
    __syncthreads();                             // the ONLY barrier

    const short* Wn = W2 + (size_t)(ln0 + node) * NODE_W2;
    const short* xn = xsh + node * 4096;
    float* ob = out + (size_t)(bn0 + node) * (S_OUT * C_OUT);

    #pragma unroll 1
    for (int q = 0; q < 4; ++q) {
        // 6 contiguous 1KB B-fragment wave-loads (independent)
        bf16x8 B[2][3];
        #pragma unroll
        for (int cc2 = 0; cc2 < 2; ++cc2)
            #pragma unroll
            for (int k = 0; k < 3; ++k)
                B[cc2][k] = *reinterpret_cast<const bf16x8*>(
                    Wn + q * 3072 + cc2 * 1536 + k * 512 + l16 * 32 + g * 8);

        const f32x4 ZV = {0.f, 0.f, 0.f, 0.f};
        f32x4 acc2[2] = {ZV, ZV};                // fresh per q, static idx
        #pragma unroll
        for (int ttl = 0; ttl < 2; ++ttl) {
            #pragma unroll
            for (int cc2 = 0; cc2 < 2; ++cc2) {
                #pragma unroll
                for (int k = 0; k < 3; ++k) {
                    int row = thalf * 32 + ttl * 16 + l16 + k;
                    row = row < 63 ? row : 63;   // t>=62 rows discarded below
                    const int so = (cc2 * 32 + g * 8) ^ ((row & 7) << 3);
                    const bf16x8 A = *reinterpret_cast<const bf16x8*>(xn + row * 64 + so);
                    acc2[ttl] = __builtin_amdgcn_mfma_f32_16x16x32_bf16(
                        A, B[cc2][k], acc2[ttl], 0, 0, 0);
                }
            }
        }
        // store this o-tile
        const int o  = q * 16 + l16;
        const float bv = bias_s[node][o];
        #pragma unroll
        for (int ttl = 0; ttl < 2; ++ttl)
            #pragma unroll
            for (int r = 0; r < 4; ++r) {
                const int t = thalf * 32 + ttl * 16 + g * 4 + r;
                if (t < S_OUT) ob[t * C_OUT + o] = acc2[ttl][r] + bv;
            }
    }
}

// ---------------- fallback: fused r6 kernel (no workspace) ----------------
#define OSTRF    104
#define WNODEF   (16 * OSTRF + 8)
#define WBUFF    (8 * WNODEF)

extern "C" __global__ void __launch_bounds__(1024, 4)
metaconv_fused_nows(const float* __restrict__ meta, const float* __restrict__ x,
                    const float* __restrict__ wlw, const float* __restrict__ wlb,
                    const float* __restrict__ blw, const float* __restrict__ blb,
                    float* __restrict__ out)
{
    __shared__ short wsh[2 * WBUFF];
    __shared__ short xshf[8 * 4096];
    __shared__ float bias_s[8][C_OUT];

    const int tid = threadIdx.x, wave = tid >> 6, lane = tid & 63;
    const int l16 = lane & 15, g = lane >> 4;
    const int node = wave & 7, thalf = wave >> 3;
    const int bn0 = blockIdx.x * 8;

    {
        const float* xsrc = x + (size_t)(bn0 + node) * (64 * C_IN);
        short* xd = xshf + node * 4096;
        const int ts0 = thalf * 32;
        #pragma unroll
        for (int i = 0; i < 4; ++i) {
            const int gi = i * 64 + lane;
            const int tl = ts0 + (gi >> 3), gr = gi & 7;
            const float4 a = *reinterpret_cast<const float4*>(xsrc + tl * 64 + gr * 8);
            const float4 b = *reinterpret_cast<const float4*>(xsrc + tl * 64 + gr * 8 + 4);
            const int so = (gr * 8) ^ ((tl & 7) << 3);
            *reinterpret_cast<bf16x8*>(xd + tl * 64 + so) = cvt8(a, b);
        }
    }
    if (tid < 8 * C_OUT) {
        const int bnode = tid >> 6, o = tid & 63;
        const float* mrow = meta + (size_t)(bn0 + bnode) * M_DIM;
        const float* brow = blw + o * M_DIM;
        float s = blb[o];
        #pragma unroll
        for (int m = 0; m < M_DIM; ++m) s += mrow[m] * brow[m];
        bias_s[bnode][o] = s;
    }
    bf16x8 metaF;
    {
        const float* mp = meta + (size_t)(bn0 + (l16 & 7)) * M_DIM + g * 8;
        metaF = cvt8(*reinterpret_cast<const float4*>(mp),
                     *reinterpret_cast<const float4*>(mp + 4));
    }
    auto hyper = [&](int c0, int oq, int buf) {
        const int og = oq * 16 + wave;
        short* wd = wsh + buf * WBUFF;
        #pragma unroll
        for (int ch = 0; ch < 2; ++ch) {
            #pragma unroll
            for (int k = 0; k < 3; ++k) {
                const int pr = og * 192 + (c0 + ch * 16 + l16) * 3 + k;
                const float* wp = wlw + (size_t)pr * M_DIM + g * 8;
                const bf16x8 aF = cvt8(*reinterpret_cast<const float4*>(wp),
                                       *reinterpret_cast<const float4*>(wp + 4));
                const int cb = c0 + ch * 16 + g * 4, pb = og * 192 + k;
                f32x4 Cf;
                Cf[0] = wlb[pb + (cb + 0) * 3]; Cf[1] = wlb[pb + (cb + 1) * 3];
                Cf[2] = wlb[pb + (cb + 2) * 3]; Cf[3] = wlb[pb + (cb + 3) * 3];
                const f32x4 d = __builtin_amdgcn_mfma_f32_16x16x32_bf16(aF, metaF, Cf, 0, 0, 0);
                if (l16 < 8) {
                    const int off = l16 * WNODEF + wave * OSTRF + k * 32 + ch * 16 + g * 4;
                    *reinterpret_cast<short4*>(&wd[off]) =
                        make_short4(f2bf(d[0]), f2bf(d[1]), f2bf(d[2]), f2bf(d[3]));
                }
            }
        }
    };
    const f32x4 ZV = {0.f, 0.f, 0.f, 0.f};
    f32x4 acc[2][4];
    #pragma unroll
    for (int t = 0; t < 2; ++t)
        #pragma unroll
        for (int o = 0; o < 4; ++o) acc[t][o] = ZV;

    hyper(0, 0, 0);
    __syncthreads();
    #pragma unroll
    for (int cc = 0; cc < 2; ++cc) {
        #pragma unroll
        for (int oq = 0; oq < 4; ++oq) {
            const int P = cc * 4 + oq;
            if (P < 7) hyper(((P + 1) >> 2) * 32, (P + 1) & 3, (P + 1) & 1);
            const short* wn = wsh + (P & 1) * WBUFF + node * WNODEF;
            const short* xn = xshf + node * 4096;
            bf16x8 B[3];
            #pragma unroll
            for (int k = 0; k < 3; ++k)
                B[k] = *reinterpret_cast<const bf16x8*>(wn + l16 * OSTRF + k * 32 + g * 8);
            #pragma unroll
            for (int ttl = 0; ttl < 2; ++ttl)
                #pragma unroll
                for (int k = 0; k < 3; ++k) {
                    int row = thalf * 32 + ttl * 16 + l16 + k;
                    row = row < 63 ? row : 63;
                    const int so = (cc * 32 + g * 8) ^ ((row & 7) << 3);
                    const bf16x8 A = *reinterpret_cast<const bf16x8*>(xn + row * 64 + so);
                    acc[ttl][oq] = __builtin_amdgcn_mfma_f32_16x16x32_bf16(
                        A, B[k], acc[ttl][oq], 0, 0, 0);
                }
            __syncthreads();
        }
    }
    float* ob = out + (size_t)(bn0 + node) * (S_OUT * C_OUT);
    #pragma unroll
    for (int ttl = 0; ttl < 2; ++ttl)
        #pragma unroll
        for (int ot = 0; ot < 4; ++ot) {
            const int o = ot * 16 + l16;
            const float bv = bias_s[node][o];
            #pragma unroll
            for (int r = 0; r < 4; ++r) {
                const int t = thalf * 32 + ttl * 16 + g * 4 + r;
                if (t < S_OUT) ob[t * C_OUT + o] = acc[ttl][ot][r] + bv;
            }
        }
}

// ---------------- launcher ----------------
extern "C" void kernel_launch(void* const* d_in, const int* in_sizes, int n_in,
                              void* d_out, int out_size, void* d_ws, size_t ws_size,
                              hipStream_t stream) {
    const float* meta = (const float*)d_in[0];
    const float* x    = (const float*)d_in[1];
    const float* wlw  = (const float*)d_in[2];
    const float* wlb  = (const float*)d_in[3];
    const float* blw  = (const float*)d_in[4];
    const float* blb  = (const float*)d_in[5];
    float* out = (float*)d_out;
    (void)in_sizes; (void)n_in; (void)out_size;

    const size_t fixed = (size_t)WLW_ROWS * M_DIM * 2 + (size_t)WLW_ROWS * 4; // 835584
    int nchunk = 0;
    for (int n = 1; n <= 8; n *= 2) {
        if (ws_size >= fixed + (size_t)(BN_TOT / n) * NODE_W2 * 2) { nchunk = n; break; }
    }

    if (nchunk) {
        short* WP    = (short*)d_ws;
        float* wlbR  = (float*)((char*)d_ws + (size_t)WLW_ROWS * M_DIM * 2);
        short* W2    = (short*)((char*)d_ws + fixed);
        wlw_perm_bf16<<<dim3(192), dim3(256), 0, stream>>>(wlw, WP);
        wlb_rearr<<<dim3(WLW_ROWS / 256), dim3(256), 0, stream>>>(wlb, wlbR);
        const int nodes = BN_TOT / nchunk;
        for (int c = 0; c < nchunk; ++c) {
            hyper_write_w<<<dim3(nodes / 16, 8), dim3(512), 0, stream>>>(
                meta, WP, wlbR, W2, c * nodes);
            conv_stream<<<dim3(nodes / 8), dim3(1024), 0, stream>>>(
                meta, x, W2, blw, blb, out, c * nodes);
        }
    } else {
        metaconv_fused_nows<<<dim3(BN_TOT / 8), dim3(1024), 0, stream>>>(
            meta, x, wlw, wlb, blw, blb, out);
    }
}

// Round 13
// 182.308 us; speedup vs baseline: 1.1988x; 1.0574x over previous
//
#include <hip/hip_runtime.h>
#include <hip/hip_bf16.h>

// MetaConv2d two-pass, round 13.
// Kernel A: hypernetwork materializes conv weights W2 into workspace in the
// EXACT B-fragment consumption order of kernel B (unchanged from r12):
//   W2[node][q][cc2][k][l16][g] bf16  (12288 shorts / node)
// Kernel B (CHANGED): software-pipelined streaming conv.
//   - B(0) fragment loads are the block's FIRST instructions (latency covered
//     by x-staging + bias work before the single barrier).
//   - q fully unrolled, two NAMED B-register sets rotated statically:
//     loadB(q+1) issues before convq(q) -> depth-1 prefetch, loads in flight
//     across the whole MFMA body. No barriers in the loop (no vmcnt drain).
//   - A-fragments read from swizzled xsh per q (LDS, conflict-free).
// r12 post-mortem: q-loop was unroll-1 -> per-q L3 latency exposed; 135us at
// 2.5TB/s with MFMA/VALU <6%. Floor ~55-60us (337MB HBM).

#define BN_TOT   8192
#define C_IN     64
#define C_OUT    64
#define M_DIM    32
#define S_OUT    62
#define WLW_ROWS 12288

#define NODE_W2  12288        // shorts per node in W2 (4q*3072)
#define A_STN    1544         // kernel A LDS node stride (8*192 + 8)

typedef __attribute__((ext_vector_type(8))) short bf16x8;
typedef __attribute__((ext_vector_type(4))) float f32x4;

static __device__ __forceinline__ short f2bf(float f) {
    return __bfloat16_as_short(__float2bfloat16(f));
}

static __device__ __forceinline__ bf16x8 cvt8(float4 a, float4 b) {
    bf16x8 r;
    r[0] = f2bf(a.x); r[1] = f2bf(a.y); r[2] = f2bf(a.z); r[3] = f2bf(a.w);
    r[4] = f2bf(b.x); r[5] = f2bf(b.y); r[6] = f2bf(b.z); r[7] = f2bf(b.w);
    return r;
}

// ---- pre-pass 1: w_lin_w f32 -> bf16, permuted to kernel A's load order ----
extern "C" __global__ void wlw_perm_bf16(const float* __restrict__ src,
                                         short* __restrict__ dst) {
    const int i = blockIdx.x * 256 + threadIdx.x;   // 49152 = 12288 rows x 4
    const int p = i >> 2;
    const int g = i & 3;
    const int o = p / 192;
    const int r = p - o * 192;
    const int c = r / 3;
    const int k = r - c * 3;
    const float4 a = *reinterpret_cast<const float4*>(src + p * 32 + g * 8);
    const float4 b = *reinterpret_cast<const float4*>(src + p * 32 + g * 8 + 4);
    const int off = o * 6144 + (c >> 4) * 1536 + k * 512 + (c & 15) * 32 + g * 8;
    *reinterpret_cast<bf16x8*>(dst + off) = cvt8(a, b);
}

// ---- pre-pass 2: wlb -> wlbR[o][k][c] f32 ----
extern "C" __global__ void wlb_rearr(const float* __restrict__ wlb,
                                     float* __restrict__ wlbR) {
    const int i = blockIdx.x * 256 + threadIdx.x;
    const int o = i / 192;
    const int r = i - o * 192;
    const int k = r >> 6;
    const int c = r & 63;
    wlbR[i] = wlb[o * 192 + c * 3 + k];
}

// ---------------- kernel A: hypernetwork -> W2 (unchanged from r12) --------
extern "C" __global__ void __launch_bounds__(512, 4)
hyper_write_w(const float* __restrict__ meta,    // [8192][32]
              const short* __restrict__ WP,      // permuted wlw bf16
              const float* __restrict__ wlbR,    // [64][3][64] f32
              short* __restrict__ W2,            // [nodes][12288] bf16
              int bn_base)
{
    __shared__ short st[16 * A_STN];             // [node][8 ow][192] (+8 pad)

    const int tid  = threadIdx.x;
    const int wave = tid >> 6;                   // ow 0..7
    const int lane = tid & 63;
    const int l16  = lane & 15;
    const int g    = lane >> 4;
    const int bn0  = bn_base + blockIdx.x * 16;
    const int og   = blockIdx.y * 8 + wave;

    bf16x8 metaF;                                // B-frag: 16 node columns
    {
        const float* mp = meta + (size_t)(bn0 + l16) * M_DIM + g * 8;
        metaF = cvt8(*reinterpret_cast<const float4*>(mp),
                     *reinterpret_cast<const float4*>(mp + 4));
    }

    #pragma unroll 1
    for (int cp = 0; cp < 2; ++cp) {
        #pragma unroll
        for (int ci = 0; ci < 2; ++ci) {
            const int ch4 = cp * 2 + ci;         // c-16-group 0..3
            #pragma unroll
            for (int k = 0; k < 3; ++k) {
                const bf16x8 aF = *reinterpret_cast<const bf16x8*>(
                    WP + og * 6144 + ch4 * 1536 + k * 512 + l16 * 32 + g * 8);
                const float4 cf = *reinterpret_cast<const float4*>(
                    wlbR + (og * 3 + k) * 64 + ch4 * 16 + g * 4);
                f32x4 Cf; Cf[0] = cf.x; Cf[1] = cf.y; Cf[2] = cf.z; Cf[3] = cf.w;
                const f32x4 d = __builtin_amdgcn_mfma_f32_16x16x32_bf16(aF, metaF, Cf, 0, 0, 0);
                *reinterpret_cast<short4*>(
                    &st[l16 * A_STN + wave * 192 + k * 64 + ch4 * 16 + g * 4]) =
                    make_short4(f2bf(d[0]), f2bf(d[1]), f2bf(d[2]), f2bf(d[3]));
            }
        }
    }
    __syncthreads();

    const int nb = blockIdx.x * 16;
    #pragma unroll
    for (int i = 0; i < 6; ++i) {
        const int u    = i * 512 + tid;
        const int node = u / 192;
        const int rem  = u - node * 192;
        const int ow   = rem / 24;
        const int rk   = rem - ow * 24;
        const int k    = rk >> 3;
        const int gb   = rk & 7;
        const int4 v = *reinterpret_cast<const int4*>(
            &st[node * A_STN + ow * 192 + k * 64 + gb * 8]);
        const int og2 = blockIdx.y * 8 + ow;
        *reinterpret_cast<int4*>(
            W2 + (size_t)(nb + node) * NODE_W2 + (og2 >> 4) * 3072 +
            (gb >> 2) * 1536 + k * 512 + (og2 & 15) * 32 + (gb & 3) * 8) = v;
    }
}

// ---------------- kernel B: pipelined streaming conv ----------------
extern "C" __global__ void __launch_bounds__(1024, 4)
conv_stream(const float* __restrict__ meta,      // [8192][32]
            const float* __restrict__ x,         // [8192][64][64]
            const short* __restrict__ W2,        // [nodes][12288] bf16 (ws)
            const float* __restrict__ blw,       // [64][32]
            const float* __restrict__ blb,       // [64]
            float* __restrict__ out,             // [8192][62][64]
            int bn_base)
{
    __shared__ short xsh[8 * 4096];              // x bf16, row-swizzled
    __shared__ float bias_s[8][C_OUT];

    const int tid   = threadIdx.x;
    const int wave  = tid >> 6;
    const int lane  = tid & 63;
    const int l16   = lane & 15;
    const int g     = lane >> 4;
    const int node  = wave & 7;
    const int thalf = wave >> 3;
    const int ln0   = blockIdx.x * 8;
    const int bn0   = bn_base + ln0;

    const short* Wn = W2 + (size_t)(ln0 + node) * NODE_W2;

    // B-fragment loader: 6 contiguous 1KB wave-loads for o-quarter q
    bf16x8 Bs0[6], Bs1[6];                        // two named sets, static rotation
    auto loadB = [&](int q, bf16x8 (&Bd)[6]) {
        #pragma unroll
        for (int cc2 = 0; cc2 < 2; ++cc2)
            #pragma unroll
            for (int k = 0; k < 3; ++k)
                Bd[cc2 * 3 + k] = *reinterpret_cast<const bf16x8*>(
                    Wn + q * 3072 + cc2 * 1536 + k * 512 + l16 * 32 + g * 8);
    };

    // ---- FIRST instructions: issue B(0) loads (covered by staging below) ----
    loadB(0, Bs0);

    // ---- stage x slab (r6 proven: swizzled, deep queue) ----
    {
        const float* xsrc = x + (size_t)(bn0 + node) * (64 * C_IN);
        short* xd = xsh + node * 4096;
        const int ts0 = thalf * 32;
        #pragma unroll
        for (int i = 0; i < 4; ++i) {
            const int gi = i * 64 + lane;
            const int tl = ts0 + (gi >> 3);
            const int gr = gi & 7;
            const float4 a = *reinterpret_cast<const float4*>(xsrc + tl * 64 + gr * 8);
            const float4 b = *reinterpret_cast<const float4*>(xsrc + tl * 64 + gr * 8 + 4);
            const int so = (gr * 8) ^ ((tl & 7) << 3);
            *reinterpret_cast<bf16x8*>(xd + tl * 64 + so) = cvt8(a, b);
        }
    }

    if (tid < 8 * C_OUT) {                       // bias table
        const int bnode = tid >> 6;
        const int o     = tid & 63;
        const float* mrow = meta + (size_t)(bn0 + bnode) * M_DIM;
        const float* brow = blw + o * M_DIM;
        float s = blb[o];
        #pragma unroll
        for (int m = 0; m < M_DIM; ++m) s += mrow[m] * brow[m];
        bias_s[bnode][o] = s;
    }
    __syncthreads();                             // the ONLY barrier

    const short* xn = xsh + node * 4096;
    float* ob = out + (size_t)(bn0 + node) * (S_OUT * C_OUT);

    // conv for one o-quarter: A from LDS, B from regs, 12 MFMA, store o-tile
    auto convq = [&](int q, bf16x8 (&Bc)[6]) {
        const f32x4 ZV = {0.f, 0.f, 0.f, 0.f};
        f32x4 acc2[2] = {ZV, ZV};                // static idx (unrolled ttl)
        #pragma unroll
        for (int ttl = 0; ttl < 2; ++ttl) {
            #pragma unroll
            for (int cc2 = 0; cc2 < 2; ++cc2) {
                #pragma unroll
                for (int k = 0; k < 3; ++k) {
                    int row = thalf * 32 + ttl * 16 + l16 + k;
                    row = row < 63 ? row : 63;   // t>=62 rows discarded below
                    const int so = (cc2 * 32 + g * 8) ^ ((row & 7) << 3);
                    const bf16x8 A = *reinterpret_cast<const bf16x8*>(xn + row * 64 + so);
                    acc2[ttl] = __builtin_amdgcn_mfma_f32_16x16x32_bf16(
                        A, Bc[cc2 * 3 + k], acc2[ttl], 0, 0, 0);
                }
            }
        }
        const int o  = q * 16 + l16;
        const float bv = bias_s[node][o];
        #pragma unroll
        for (int ttl = 0; ttl < 2; ++ttl)
            #pragma unroll
            for (int r = 0; r < 4; ++r) {
                const int t = thalf * 32 + ttl * 16 + g * 4 + r;
                if (t < S_OUT) ob[t * C_OUT + o] = acc2[ttl][r] + bv;
            }
    };

    // ---- fully-unrolled pipelined schedule (depth-1 B prefetch) ----
    loadB(1, Bs1);
    convq(0, Bs0);
    loadB(2, Bs0);
    convq(1, Bs1);
    loadB(3, Bs1);
    convq(2, Bs0);
    convq(3, Bs1);
}

// ---------------- fallback: fused r6 kernel (no workspace) ----------------
#define OSTRF    104
#define WNODEF   (16 * OSTRF + 8)
#define WBUFF    (8 * WNODEF)

extern "C" __global__ void __launch_bounds__(1024, 4)
metaconv_fused_nows(const float* __restrict__ meta, const float* __restrict__ x,
                    const float* __restrict__ wlw, const float* __restrict__ wlb,
                    const float* __restrict__ blw, const float* __restrict__ blb,
                    float* __restrict__ out)
{
    __shared__ short wsh[2 * WBUFF];
    __shared__ short xshf[8 * 4096];
    __shared__ float bias_s[8][C_OUT];

    const int tid = threadIdx.x, wave = tid >> 6, lane = tid & 63;
    const int l16 = lane & 15, g = lane >> 4;
    const int node = wave & 7, thalf = wave >> 3;
    const int bn0 = blockIdx.x * 8;

    {
        const float* xsrc = x + (size_t)(bn0 + node) * (64 * C_IN);
        short* xd = xshf + node * 4096;
        const int ts0 = thalf * 32;
        #pragma unroll
        for (int i = 0; i < 4; ++i) {
            const int gi = i * 64 + lane;
            const int tl = ts0 + (gi >> 3), gr = gi & 7;
            const float4 a = *reinterpret_cast<const float4*>(xsrc + tl * 64 + gr * 8);
            const float4 b = *reinterpret_cast<const float4*>(xsrc + tl * 64 + gr * 8 + 4);
            const int so = (gr * 8) ^ ((tl & 7) << 3);
            *reinterpret_cast<bf16x8*>(xd + tl * 64 + so) = cvt8(a, b);
        }
    }
    if (tid < 8 * C_OUT) {
        const int bnode = tid >> 6, o = tid & 63;
        const float* mrow = meta + (size_t)(bn0 + bnode) * M_DIM;
        const float* brow = blw + o * M_DIM;
        float s = blb[o];
        #pragma unroll
        for (int m = 0; m < M_DIM; ++m) s += mrow[m] * brow[m];
        bias_s[bnode][o] = s;
    }
    bf16x8 metaF;
    {
        const float* mp = meta + (size_t)(bn0 + (l16 & 7)) * M_DIM + g * 8;
        metaF = cvt8(*reinterpret_cast<const float4*>(mp),
                     *reinterpret_cast<const float4*>(mp + 4));
    }
    auto hyper = [&](int c0, int oq, int buf) {
        const int og = oq * 16 + wave;
        short* wd = wsh + buf * WBUFF;
        #pragma unroll
        for (int ch = 0; ch < 2; ++ch) {
            #pragma unroll
            for (int k = 0; k < 3; ++k) {
                const int pr = og * 192 + (c0 + ch * 16 + l16) * 3 + k;
                const float* wp = wlw + (size_t)pr * M_DIM + g * 8;
                const bf16x8 aF = cvt8(*reinterpret_cast<const float4*>(wp),
                                       *reinterpret_cast<const float4*>(wp + 4));
                const int cb = c0 + ch * 16 + g * 4, pb = og * 192 + k;
                f32x4 Cf;
                Cf[0] = wlb[pb + (cb + 0) * 3]; Cf[1] = wlb[pb + (cb + 1) * 3];
                Cf[2] = wlb[pb + (cb + 2) * 3]; Cf[3] = wlb[pb + (cb + 3) * 3];
                const f32x4 d = __builtin_amdgcn_mfma_f32_16x16x32_bf16(aF, metaF, Cf, 0, 0, 0);
                if (l16 < 8) {
                    const int off = l16 * WNODEF + wave * OSTRF + k * 32 + ch * 16 + g * 4;
                    *reinterpret_cast<short4*>(&wd[off]) =
                        make_short4(f2bf(d[0]), f2bf(d[1]), f2bf(d[2]), f2bf(d[3]));
                }
            }
        }
    };
    const f32x4 ZV = {0.f, 0.f, 0.f, 0.f};
    f32x4 acc[2][4];
    #pragma unroll
    for (int t = 0; t < 2; ++t)
        #pragma unroll
        for (int o = 0; o < 4; ++o) acc[t][o] = ZV;

    hyper(0, 0, 0);
    __syncthreads();
    #pragma unroll
    for (int cc = 0; cc < 2; ++cc) {
        #pragma unroll
        for (int oq = 0; oq < 4; ++oq) {
            const int P = cc * 4 + oq;
            if (P < 7) hyper(((P + 1) >> 2) * 32, (P + 1) & 3, (P + 1) & 1);
            const short* wn = wsh + (P & 1) * WBUFF + node * WNODEF;
            const short* xn = xshf + node * 4096;
            bf16x8 B[3];
            #pragma unroll
            for (int k = 0; k < 3; ++k)
                B[k] = *reinterpret_cast<const bf16x8*>(wn + l16 * OSTRF + k * 32 + g * 8);
            #pragma unroll
            for (int ttl = 0; ttl < 2; ++ttl)
                #pragma unroll
                for (int k = 0; k < 3; ++k) {
                    int row = thalf * 32 + ttl * 16 + l16 + k;
                    row = row < 63 ? row : 63;
                    const int so = (cc * 32 + g * 8) ^ ((row & 7) << 3);
                    const bf16x8 A = *reinterpret_cast<const bf16x8*>(xn + row * 64 + so);
                    acc[ttl][oq] = __builtin_amdgcn_mfma_f32_16x16x32_bf16(
                        A, B[k], acc[ttl][oq], 0, 0, 0);
                }
            __syncthreads();
        }
    }
    float* ob = out + (size_t)(bn0 + node) * (S_OUT * C_OUT);
    #pragma unroll
    for (int ttl = 0; ttl < 2; ++ttl)
        #pragma unroll
        for (int ot = 0; ot < 4; ++ot) {
            const int o = ot * 16 + l16;
            const float bv = bias_s[node][o];
            #pragma unroll
            for (int r = 0; r < 4; ++r) {
                const int t = thalf * 32 + ttl * 16 + g * 4 + r;
                if (t < S_OUT) ob[t * C_OUT + o] = acc[ttl][ot][r] + bv;
            }
        }
}

// ---------------- launcher ----------------
extern "C" void kernel_launch(void* const* d_in, const int* in_sizes, int n_in,
                              void* d_out, int out_size, void* d_ws, size_t ws_size,
                              hipStream_t stream) {
    const float* meta = (const float*)d_in[0];
    const float* x    = (const float*)d_in[1];
    const float* wlw  = (const float*)d_in[2];
    const float* wlb  = (const float*)d_in[3];
    const float* blw  = (const float*)d_in[4];
    const float* blb  = (const float*)d_in[5];
    float* out = (float*)d_out;
    (void)in_sizes; (void)n_in; (void)out_size;

    const size_t fixed = (size_t)WLW_ROWS * M_DIM * 2 + (size_t)WLW_ROWS * 4; // 835584
    int nchunk = 0;
    for (int n = 1; n <= 8; n *= 2) {
        if (ws_size >= fixed + (size_t)(BN_TOT / n) * NODE_W2 * 2) { nchunk = n; break; }
    }

    if (nchunk) {
        short* WP    = (short*)d_ws;
        float* wlbR  = (float*)((char*)d_ws + (size_t)WLW_ROWS * M_DIM * 2);
        short* W2    = (short*)((char*)d_ws + fixed);
        wlw_perm_bf16<<<dim3(192), dim3(256), 0, stream>>>(wlw, WP);
        wlb_rearr<<<dim3(WLW_ROWS / 256), dim3(256), 0, stream>>>(wlb, wlbR);
        const int nodes = BN_TOT / nchunk;
        for (int c = 0; c < nchunk; ++c) {
            hyper_write_w<<<dim3(nodes / 16, 8), dim3(512), 0, stream>>>(
                meta, WP, wlbR, W2, c * nodes);
            conv_stream<<<dim3(nodes / 8), dim3(1024), 0, stream>>>(
                meta, x, W2, blw, blb, out, c * nodes);
        }
    } else {
        metaconv_fused_nows<<<dim3(BN_TOT / 8), dim3(1024), 0, stream>>>(
            meta, x, wlw, wlb, blw, blb, out);
    }
}